// Round 3
// baseline (206.890 us; speedup 1.0000x reference)
//
#include <hip/hip_runtime.h>

#define B 4
#define N 4096
#define M 4096
#define C 32
#define BN (B * N)

typedef short bf16x8 __attribute__((ext_vector_type(8)));  // 8 bf16 in 4 VGPRs
typedef float f32x4  __attribute__((ext_vector_type(4)));
typedef unsigned int u32x4 __attribute__((ext_vector_type(4)));

// Workspace layout (bytes). Total ~4.1 MB (poisoned by harness each iter; all
// consumed state is written before read within this launch sequence).
#define WS_WI ((size_t)8 * BN * 4)                       // wD @ 0, wI @ WS_WI
#define WS_YH (WS_WI * 2)                                // bf16 hi plane of y
#define WS_YM (WS_YH + (size_t)B * M * C * 2)            // mid plane
#define WS_YL (WS_YM + (size_t)B * M * C * 2)            // lo plane
#define WS_Y2 (WS_YL + (size_t)B * M * C * 2)            // -0.5*y2 (f32)
#define WS_CT (WS_Y2 + (size_t)B * M * 4)                // 128 group counters

__device__ __forceinline__ float bf16lo(unsigned int u) { return __uint_as_float(u << 16); }
__device__ __forceinline__ float bf16hi(unsigned int u) { return __uint_as_float(u & 0xffff0000u); }

// Exact 3-way truncation split of 8 f32 values into 3 bf16x8 planes.
// f32 mantissa = 24 bits; each plane captures >=8 bits and each residual
// subtraction is exact, so f = h + m + l EXACTLY.
__device__ __forceinline__ void split3(const float f[8], bf16x8& h, bf16x8& m, bf16x8& l) {
    u32x4 hw, mw, lw;
    #pragma unroll
    for (int p = 0; p < 4; ++p) {
        const float f0 = f[2*p], f1 = f[2*p+1];
        const unsigned int h0 = __float_as_uint(f0) & 0xffff0000u;
        const unsigned int h1 = __float_as_uint(f1) & 0xffff0000u;
        hw[p] = h1 | (h0 >> 16);
        const float r0 = f0 - __uint_as_float(h0);
        const float r1 = f1 - __uint_as_float(h1);
        const unsigned int m0 = __float_as_uint(r0) & 0xffff0000u;
        const unsigned int m1 = __float_as_uint(r1) & 0xffff0000u;
        mw[p] = m1 | (m0 >> 16);
        const float s0 = r0 - __uint_as_float(m0);
        const float s1 = r1 - __uint_as_float(m1);
        lw[p] = (__float_as_uint(s1) & 0xffff0000u) | (__float_as_uint(s0) >> 16);
    }
    h = __builtin_bit_cast(bf16x8, hw);
    m = __builtin_bit_cast(bf16x8, mw);
    l = __builtin_bit_cast(bf16x8, lw);
}

// Pre-pass: zero the group counters (workspace is poisoned between iters),
// then (f32 mode only) split y into 3 bf16 planes + compute -0.5*y2.
// Grid: 256 blocks x 256 threads = 65536 = B*M*4; each thread handles 8 elems.
__global__ __launch_bounds__(256)
void y_prepass(const void* __restrict__ yptr, const unsigned short* __restrict__ tptr,
               void* __restrict__ ws) {
    const int gid = blockIdx.x * 256 + threadIdx.x;
    int* ctr = (int*)((char*)ws + WS_CT);
    if (gid < 128) ctr[gid] = 0;
    if (tptr[0] == 0x4120) return;   // bf16 inputs: planes unused

    unsigned short* yh = (unsigned short*)((char*)ws + WS_YH);
    unsigned short* ym = (unsigned short*)((char*)ws + WS_YM);
    unsigned short* yl = (unsigned short*)((char*)ws + WS_YL);
    float*          y2 = (float*)((char*)ws + WS_Y2);

    const int row = gid >> 2;
    const int seg = gid & 3;
    const float* p = (const float*)yptr + (size_t)row * C + seg * 8;
    float4 v0 = *(const float4*)p;
    float4 v1 = *(const float4*)(p + 4);
    const float f[8] = {v0.x, v0.y, v0.z, v0.w, v1.x, v1.y, v1.z, v1.w};

    bf16x8 h, m, l;
    split3(f, h, m, l);
    const size_t o = (size_t)row * C + seg * 8;
    *(bf16x8*)(yh + o) = h;
    *(bf16x8*)(ym + o) = m;
    *(bf16x8*)(yl + o) = l;

    float s = 0.f;
    #pragma unroll
    for (int k = 0; k < 8; ++k) s = fmaf(f[k], f[k], s);
    s += __shfl_xor(s, 1, 64);     // 4 consecutive lanes share a row
    s += __shfl_xor(s, 2, 64);
    if (seg == 0) y2[row] = -0.5f * s;
}

// Grid: 1024 blocks x 256 threads (4 blocks/CU, 16 waves/CU).
// bi -> ms = bi&7 (m-split of 512), nb = (bi>>3)&31 (128 n rows), b = bi>>8.
// Each wave: 32 n rows (2 MFMA n-tiles), scans 512 m via 32 m-tiles.
// Key = dot - y2/2 (argmax == argmin dist; x2 cancels). C-operand seeds -y2/2.
// f32 path: 6 MFMA terms (hh,hm,mh,mm,hl,lh). Dropped ml/lm/ll terms are
// <= ~3e-7 absolute -- an order below the f32 accumulation noise (~7e-6) both
// the reference and the verified 9-term kernel carry -> argmax-neutral.
// The 8 blocks of each (b,nb) group combine via last-block pattern (counter
// zeroed by y_prepass), eliminating the separate combine kernel.
__global__ __launch_bounds__(256, 4)
void nn_main(const void* __restrict__ xptr, const void* __restrict__ yptr,
             const void* __restrict__ ycptr, const unsigned short* __restrict__ tptr,
             void* __restrict__ ws, void* __restrict__ outptr) {
    float* wD = (float*)ws;
    int*   wI = (int*)((char*)ws + WS_WI);
    const bool is_bf16 = (tptr[0] == 0x4120);  // bf16(10.0)=0x4120; f32 low half = 0x0000

    __shared__ float y2s[512];          // -0.5*y2 for this m-split
    __shared__ int   lastFlag;

    const int tid  = threadIdx.x;
    const int lane = tid & 63;
    const int wv   = tid >> 6;
    const int col  = lane & 15;
    const int quad = lane >> 4;
    const int bi   = blockIdx.x;
    const int ms   = bi & 7;
    const int nb   = (bi >> 3) & 31;
    const int b    = bi >> 8;
    const int n_base = nb * 128 + wv * 32;

    float bD[2][4];
    int   bI[2][4];
    #pragma unroll
    for (int t = 0; t < 2; ++t)
        #pragma unroll
        for (int r = 0; r < 4; ++r) { bD[t][r] = -__builtin_inff(); bI[t][r] = 0; }

    const size_t boff = (size_t)col * C + quad * 8;

    if (is_bf16) {
        const unsigned short* yp = (const unsigned short*)yptr;
        const unsigned short* xp = (const unsigned short*)xptr;

        // ---- stage -0.5*y2 for the 512 m rows of this split ----
        for (int r = tid; r < 512; r += 256) {
            const int m = ms * 512 + r;
            const uint4* p = (const uint4*)(yp + ((size_t)b * M + m) * C);
            float s = 0.f;
            #pragma unroll
            for (int i = 0; i < 4; ++i) {
                uint4 v = p[i];
                float f;
                f = bf16lo(v.x); s = fmaf(f, f, s); f = bf16hi(v.x); s = fmaf(f, f, s);
                f = bf16lo(v.y); s = fmaf(f, f, s); f = bf16hi(v.y); s = fmaf(f, f, s);
                f = bf16lo(v.z); s = fmaf(f, f, s); f = bf16hi(v.z); s = fmaf(f, f, s);
                f = bf16lo(v.w); s = fmaf(f, f, s); f = bf16hi(v.w); s = fmaf(f, f, s);
            }
            y2s[r] = -0.5f * s;
        }

        bf16x8 af[2];
        #pragma unroll
        for (int t = 0; t < 2; ++t)
            af[t] = *(const bf16x8*)(xp + ((size_t)b * N + n_base + t * 16 + col) * C + quad * 8);

        __syncthreads();

        const unsigned short* yb = yp + ((size_t)b * M + ms * 512) * C;
        bf16x8 bfr = *(const bf16x8*)(yb + boff);
        for (int mt = 0; mt < 32; ++mt) {
            bf16x8 bnx = bfr;
            if (mt < 31) bnx = *(const bf16x8*)(yb + boff + (size_t)(mt + 1) * (16 * C));
            const float y2c  = y2s[mt * 16 + col];
            const int   mcur = ms * 512 + mt * 16 + col;
            #pragma unroll
            for (int t = 0; t < 2; ++t) {
                f32x4 acc = {y2c, y2c, y2c, y2c};
                acc = __builtin_amdgcn_mfma_f32_16x16x32_bf16(af[t], bfr, acc, 0, 0, 0);
                #pragma unroll
                for (int r = 0; r < 4; ++r)
                    if (acc[r] > bD[t][r]) { bD[t][r] = acc[r]; bI[t][r] = mcur; }
            }
            bfr = bnx;
        }
    } else {
        // ============ f32 path: pre-split planes, 6 MFMA terms ============
        const unsigned short* yh = (const unsigned short*)((char*)ws + WS_YH) + ((size_t)b * M + ms * 512) * C;
        const unsigned short* ym = (const unsigned short*)((char*)ws + WS_YM) + ((size_t)b * M + ms * 512) * C;
        const unsigned short* yl = (const unsigned short*)((char*)ws + WS_YL) + ((size_t)b * M + ms * 512) * C;
        const float*         y2g = (const float*)((char*)ws + WS_Y2) + (size_t)b * M + ms * 512;

        for (int r = tid; r < 512; r += 256) y2s[r] = y2g[r];

        // A fragments: 3 planes per tile, split once in registers
        const float* xp = (const float*)xptr;
        bf16x8 ah[2], am[2], al[2];
        #pragma unroll
        for (int t = 0; t < 2; ++t) {
            const float* xr = xp + ((size_t)b * N + n_base + t * 16 + col) * C + quad * 8;
            float4 v0 = *(const float4*)xr;
            float4 v1 = *(const float4*)(xr + 4);
            const float xf[8] = {v0.x, v0.y, v0.z, v0.w, v1.x, v1.y, v1.z, v1.w};
            split3(xf, ah[t], am[t], al[t]);
        }

        __syncthreads();

        bf16x8 bh  = *(const bf16x8*)(yh + boff);
        bf16x8 bmi = *(const bf16x8*)(ym + boff);
        bf16x8 bl  = *(const bf16x8*)(yl + boff);
        for (int mt = 0; mt < 32; ++mt) {
            bf16x8 nh = bh, nm = bmi, nl = bl;
            if (mt < 31) {
                const size_t no = boff + (size_t)(mt + 1) * (16 * C);
                nh = *(const bf16x8*)(yh + no);
                nm = *(const bf16x8*)(ym + no);
                nl = *(const bf16x8*)(yl + no);
            }
            const float y2c  = y2s[mt * 16 + col];
            const int   mcur = ms * 512 + mt * 16 + col;
            #pragma unroll
            for (int t = 0; t < 2; ++t) {
                f32x4 acc = {y2c, y2c, y2c, y2c};
                // 6 kept cross-terms, small-magnitude first
                acc = __builtin_amdgcn_mfma_f32_16x16x32_bf16(am[t], bmi, acc, 0, 0, 0);
                acc = __builtin_amdgcn_mfma_f32_16x16x32_bf16(ah[t], bl,  acc, 0, 0, 0);
                acc = __builtin_amdgcn_mfma_f32_16x16x32_bf16(al[t], bh,  acc, 0, 0, 0);
                acc = __builtin_amdgcn_mfma_f32_16x16x32_bf16(ah[t], bmi, acc, 0, 0, 0);
                acc = __builtin_amdgcn_mfma_f32_16x16x32_bf16(am[t], bh,  acc, 0, 0, 0);
                acc = __builtin_amdgcn_mfma_f32_16x16x32_bf16(ah[t], bh,  acc, 0, 0, 0);
                #pragma unroll
                for (int r = 0; r < 4; ++r)
                    if (acc[r] > bD[t][r]) { bD[t][r] = acc[r]; bI[t][r] = mcur; }
            }
            bh = nh; bmi = nm; bl = nl;
        }
    }

    // ---- butterfly over the 16 col-classes (lanes quad*16 + 0..15) ----
    #pragma unroll
    for (int mask = 1; mask < 16; mask <<= 1) {
        #pragma unroll
        for (int t = 0; t < 2; ++t)
            #pragma unroll
            for (int r = 0; r < 4; ++r) {
                float oD = __shfl_xor(bD[t][r], mask, 64);
                int   oI = __shfl_xor(bI[t][r], mask, 64);
                if (oD > bD[t][r] || (oD == bD[t][r] && oI < bI[t][r])) {
                    bD[t][r] = oD; bI[t][r] = oI;
                }
            }
    }

    // tracker (t,r) of lane-group quad holds row n_base + t*16 + quad*4 + r
    if (col == 0) {
        #pragma unroll
        for (int t = 0; t < 2; ++t)
            #pragma unroll
            for (int r = 0; r < 4; ++r) {
                const int n = n_base + t * 16 + quad * 4 + r;
                const size_t g = (size_t)ms * BN + (size_t)b * N + n;
                wD[g] = bD[t][r];
                wI[g] = bI[t][r];
            }
    }

    // ---- last-block combine for this (b,nb) group (8 ms-blocks) ----
    __threadfence();                       // release this block's slot writes
    __syncthreads();
    if (tid == 0) {
        int* ctr = (int*)((char*)ws + WS_CT);
        lastFlag = (atomicAdd(&ctr[bi >> 3], 1) == 7);
    }
    __syncthreads();
    if (lastFlag) {
        __threadfence();                   // acquire the other blocks' writes
        const int row0 = (bi >> 3) * 128;  // == b*N + nb*128
        const int s    = tid & 7;
        #pragma unroll
        for (int p = 0; p < 4; ++p) {
            const int row = row0 + p * 32 + (tid >> 3);
            float k  = wD[(size_t)s * BN + row];
            int   ix = wI[(size_t)s * BN + row];
            #pragma unroll
            for (int mask = 1; mask < 8; mask <<= 1) {
                float ok = __shfl_xor(k, mask, 64);
                int   oi = __shfl_xor(ix, mask, 64);
                if (ok > k || (ok == k && oi < ix)) { k = ok; ix = oi; }
            }
            if (s == 0) {
                const int bb = row >> 12;  // N = 4096
                const size_t src = ((size_t)bb * M + ix) * 3;
                if (is_bf16) {
                    const unsigned short* yc = (const unsigned short*)ycptr;
                    unsigned short* o = (unsigned short*)outptr;
                    o[row*3+0] = yc[src+0];
                    o[row*3+1] = yc[src+1];
                    o[row*3+2] = yc[src+2];
                } else {
                    const float* yc = (const float*)ycptr;
                    float* o = (float*)outptr;
                    o[row*3+0] = yc[src+0];
                    o[row*3+1] = yc[src+1];
                    o[row*3+2] = yc[src+2];
                }
            }
        }
    }
}

extern "C" void kernel_launch(void* const* d_in, const int* in_sizes, int n_in,
                              void* d_out, int out_size, void* d_ws, size_t ws_size,
                              hipStream_t stream) {
    const void* x  = d_in[0];
    const void* y  = d_in[1];
    const void* yc = d_in[2];
    const unsigned short* t = (const unsigned short*)d_in[3];

    y_prepass<<<256, 256, 0, stream>>>(y, t, d_ws);
    nn_main<<<1024, 256, 0, stream>>>(x, y, yc, t, d_ws, d_out);
}

// Round 4
// 99.858 us; speedup vs baseline: 2.0718x; 2.0718x over previous
//
#include <hip/hip_runtime.h>

#define B 4
#define N 4096
#define M 4096
#define C 32
#define BN (B * N)
#define MS 16            // m-splits; each split covers M/MS = 256 rows = 16 m-tiles

typedef short bf16x8 __attribute__((ext_vector_type(8)));  // 8 bf16 in 4 VGPRs
typedef float f32x4  __attribute__((ext_vector_type(4)));
typedef unsigned int u32x4 __attribute__((ext_vector_type(4)));

// Workspace layout (bytes). ~5.1 MB. wD/wI are [row][slot] (slot-minor) so the
// combine kernel's reads are fully coalesced.
#define WS_WI ((size_t)MS * BN * 4)                      // wD @ 0, wI @ WS_WI
#define WS_YH (WS_WI * 2)                                // bf16 hi plane of y
#define WS_YM (WS_YH + (size_t)B * M * C * 2)            // mid plane
#define WS_YL (WS_YM + (size_t)B * M * C * 2)            // lo plane
#define WS_Y2 (WS_YL + (size_t)B * M * C * 2)            // -0.5*y2 (f32)

__device__ __forceinline__ float bf16lo(unsigned int u) { return __uint_as_float(u << 16); }
__device__ __forceinline__ float bf16hi(unsigned int u) { return __uint_as_float(u & 0xffff0000u); }

// Exact 3-way truncation split of 8 f32 values into 3 bf16x8 planes.
// f32 mantissa = 24 bits; each plane captures >=8 bits and each residual
// subtraction is exact, so f = h + m + l EXACTLY.
__device__ __forceinline__ void split3(const float f[8], bf16x8& h, bf16x8& m, bf16x8& l) {
    u32x4 hw, mw, lw;
    #pragma unroll
    for (int p = 0; p < 4; ++p) {
        const float f0 = f[2*p], f1 = f[2*p+1];
        const unsigned int h0 = __float_as_uint(f0) & 0xffff0000u;
        const unsigned int h1 = __float_as_uint(f1) & 0xffff0000u;
        hw[p] = h1 | (h0 >> 16);
        const float r0 = f0 - __uint_as_float(h0);
        const float r1 = f1 - __uint_as_float(h1);
        const unsigned int m0 = __float_as_uint(r0) & 0xffff0000u;
        const unsigned int m1 = __float_as_uint(r1) & 0xffff0000u;
        mw[p] = m1 | (m0 >> 16);
        const float s0 = r0 - __uint_as_float(m0);
        const float s1 = r1 - __uint_as_float(m1);
        lw[p] = (__float_as_uint(s1) & 0xffff0000u) | (__float_as_uint(s0) >> 16);
    }
    h = __builtin_bit_cast(bf16x8, hw);
    m = __builtin_bit_cast(bf16x8, mw);
    l = __builtin_bit_cast(bf16x8, lw);
}

// Pre-pass (f32 mode only): split y into 3 bf16 planes + compute -0.5*y2.
// Grid: 256 blocks x 256 threads = 65536 = B*M*4; each thread handles 8 elems.
__global__ __launch_bounds__(256)
void y_prepass(const void* __restrict__ yptr, const unsigned short* __restrict__ tptr,
               void* __restrict__ ws) {
    if (tptr[0] == 0x4120) return;   // bf16 inputs: planes unused
    unsigned short* yh = (unsigned short*)((char*)ws + WS_YH);
    unsigned short* ym = (unsigned short*)((char*)ws + WS_YM);
    unsigned short* yl = (unsigned short*)((char*)ws + WS_YL);
    float*          y2 = (float*)((char*)ws + WS_Y2);

    const int gid = blockIdx.x * 256 + threadIdx.x;
    const int row = gid >> 2;
    const int seg = gid & 3;
    const float* p = (const float*)yptr + (size_t)row * C + seg * 8;
    float4 v0 = *(const float4*)p;
    float4 v1 = *(const float4*)(p + 4);
    const float f[8] = {v0.x, v0.y, v0.z, v0.w, v1.x, v1.y, v1.z, v1.w};

    bf16x8 h, m, l;
    split3(f, h, m, l);
    const size_t o = (size_t)row * C + seg * 8;
    *(bf16x8*)(yh + o) = h;
    *(bf16x8*)(ym + o) = m;
    *(bf16x8*)(yl + o) = l;

    float s = 0.f;
    #pragma unroll
    for (int k = 0; k < 8; ++k) s = fmaf(f[k], f[k], s);
    s += __shfl_xor(s, 1, 64);     // 4 consecutive lanes share a row
    s += __shfl_xor(s, 2, 64);
    if (seg == 0) y2[row] = -0.5f * s;
}

// Grid: 2048 blocks x 256 threads (8 blocks/CU at VGPR<=64 -> 32 waves/CU).
// bi -> ms = bi&15 (m-split of 256), nb = (bi>>4)&31 (128 n rows), b = bi>>9.
// Each wave: 32 n rows (2 MFMA n-tiles), scans 256 m via 16 m-tiles.
// Key = dot - y2/2 (argmax == argmin dist; x2 cancels). C-operand seeds -y2/2.
// f32 path: 6 MFMA terms (hh,hm,mh,mm,hl,lh); dropped ml/lm/ll are <=~3e-7,
// an order below the f32 accumulation noise (~7e-6) the reference itself
// carries -> argmax-neutral (harness-verified in the previous round).
__global__ __launch_bounds__(256, 4)
void nn_main(const void* __restrict__ xptr, const void* __restrict__ yptr,
             const unsigned short* __restrict__ tptr, void* __restrict__ ws) {
    float* wD = (float*)ws;
    int*   wI = (int*)((char*)ws + WS_WI);
    const bool is_bf16 = (tptr[0] == 0x4120);  // bf16(10.0)=0x4120; f32 low half = 0x0000

    __shared__ float y2s[256];          // -0.5*y2 for this m-split

    const int tid  = threadIdx.x;
    const int lane = tid & 63;
    const int wv   = tid >> 6;
    const int col  = lane & 15;
    const int quad = lane >> 4;
    const int bi   = blockIdx.x;
    const int ms   = bi & 15;
    const int nb   = (bi >> 4) & 31;
    const int b    = bi >> 9;
    const int n_base = nb * 128 + wv * 32;
    const int m0   = ms * 256;

    float bD[2][4];
    int   bI[2][4];
    #pragma unroll
    for (int t = 0; t < 2; ++t)
        #pragma unroll
        for (int r = 0; r < 4; ++r) { bD[t][r] = -__builtin_inff(); bI[t][r] = 0; }

    const size_t boff = (size_t)col * C + quad * 8;

    if (is_bf16) {
        const unsigned short* yp = (const unsigned short*)yptr;
        const unsigned short* xp = (const unsigned short*)xptr;

        // ---- stage -0.5*y2 for the 256 m rows of this split ----
        if (tid < 256) {
            const int r = tid;
            const uint4* p = (const uint4*)(yp + ((size_t)b * M + m0 + r) * C);
            float s = 0.f;
            #pragma unroll
            for (int i = 0; i < 4; ++i) {
                uint4 v = p[i];
                float f;
                f = bf16lo(v.x); s = fmaf(f, f, s); f = bf16hi(v.x); s = fmaf(f, f, s);
                f = bf16lo(v.y); s = fmaf(f, f, s); f = bf16hi(v.y); s = fmaf(f, f, s);
                f = bf16lo(v.z); s = fmaf(f, f, s); f = bf16hi(v.z); s = fmaf(f, f, s);
                f = bf16lo(v.w); s = fmaf(f, f, s); f = bf16hi(v.w); s = fmaf(f, f, s);
            }
            y2s[r] = -0.5f * s;
        }

        bf16x8 af[2];
        #pragma unroll
        for (int t = 0; t < 2; ++t)
            af[t] = *(const bf16x8*)(xp + ((size_t)b * N + n_base + t * 16 + col) * C + quad * 8);

        __syncthreads();

        const unsigned short* yb = yp + ((size_t)b * M + m0) * C;
        bf16x8 bfr = *(const bf16x8*)(yb + boff);
        for (int mt = 0; mt < 16; ++mt) {
            bf16x8 bnx = bfr;
            if (mt < 15) bnx = *(const bf16x8*)(yb + boff + (size_t)(mt + 1) * (16 * C));
            const float y2c  = y2s[mt * 16 + col];
            const int   mcur = m0 + mt * 16 + col;
            #pragma unroll
            for (int t = 0; t < 2; ++t) {
                f32x4 acc = {y2c, y2c, y2c, y2c};
                acc = __builtin_amdgcn_mfma_f32_16x16x32_bf16(af[t], bfr, acc, 0, 0, 0);
                #pragma unroll
                for (int r = 0; r < 4; ++r)
                    if (acc[r] > bD[t][r]) { bD[t][r] = acc[r]; bI[t][r] = mcur; }
            }
            bfr = bnx;
        }
    } else {
        // ============ f32 path: pre-split planes, 6 MFMA terms ============
        const unsigned short* yh = (const unsigned short*)((char*)ws + WS_YH) + ((size_t)b * M + m0) * C;
        const unsigned short* ym = (const unsigned short*)((char*)ws + WS_YM) + ((size_t)b * M + m0) * C;
        const unsigned short* yl = (const unsigned short*)((char*)ws + WS_YL) + ((size_t)b * M + m0) * C;
        const float*         y2g = (const float*)((char*)ws + WS_Y2) + (size_t)b * M + m0;

        if (tid < 256) y2s[tid] = y2g[tid];

        // A fragments: 3 planes per tile, split once in registers
        const float* xp = (const float*)xptr;
        bf16x8 ah[2], am[2], al[2];
        #pragma unroll
        for (int t = 0; t < 2; ++t) {
            const float* xr = xp + ((size_t)b * N + n_base + t * 16 + col) * C + quad * 8;
            float4 v0 = *(const float4*)xr;
            float4 v1 = *(const float4*)(xr + 4);
            const float xf[8] = {v0.x, v0.y, v0.z, v0.w, v1.x, v1.y, v1.z, v1.w};
            split3(xf, ah[t], am[t], al[t]);
        }

        __syncthreads();

        bf16x8 bh  = *(const bf16x8*)(yh + boff);
        bf16x8 bmi = *(const bf16x8*)(ym + boff);
        bf16x8 bl  = *(const bf16x8*)(yl + boff);
        for (int mt = 0; mt < 16; ++mt) {
            bf16x8 nh = bh, nm = bmi, nl = bl;
            if (mt < 15) {
                const size_t no = boff + (size_t)(mt + 1) * (16 * C);
                nh = *(const bf16x8*)(yh + no);
                nm = *(const bf16x8*)(ym + no);
                nl = *(const bf16x8*)(yl + no);
            }
            const float y2c  = y2s[mt * 16 + col];
            const int   mcur = m0 + mt * 16 + col;
            #pragma unroll
            for (int t = 0; t < 2; ++t) {
                f32x4 acc = {y2c, y2c, y2c, y2c};
                // 6 kept cross-terms, small-magnitude first
                acc = __builtin_amdgcn_mfma_f32_16x16x32_bf16(am[t], bmi, acc, 0, 0, 0);
                acc = __builtin_amdgcn_mfma_f32_16x16x32_bf16(ah[t], bl,  acc, 0, 0, 0);
                acc = __builtin_amdgcn_mfma_f32_16x16x32_bf16(al[t], bh,  acc, 0, 0, 0);
                acc = __builtin_amdgcn_mfma_f32_16x16x32_bf16(ah[t], bmi, acc, 0, 0, 0);
                acc = __builtin_amdgcn_mfma_f32_16x16x32_bf16(am[t], bh,  acc, 0, 0, 0);
                acc = __builtin_amdgcn_mfma_f32_16x16x32_bf16(ah[t], bh,  acc, 0, 0, 0);
                #pragma unroll
                for (int r = 0; r < 4; ++r)
                    if (acc[r] > bD[t][r]) { bD[t][r] = acc[r]; bI[t][r] = mcur; }
            }
            bh = nh; bmi = nm; bl = nl;
        }
    }

    // ---- butterfly over the 16 col-classes (lanes quad*16 + 0..15) ----
    #pragma unroll
    for (int mask = 1; mask < 16; mask <<= 1) {
        #pragma unroll
        for (int t = 0; t < 2; ++t)
            #pragma unroll
            for (int r = 0; r < 4; ++r) {
                float oD = __shfl_xor(bD[t][r], mask, 64);
                int   oI = __shfl_xor(bI[t][r], mask, 64);
                if (oD > bD[t][r] || (oD == bD[t][r] && oI < bI[t][r])) {
                    bD[t][r] = oD; bI[t][r] = oI;
                }
            }
    }

    // tracker (t,r) of lane-group quad holds row n_base + t*16 + quad*4 + r
    if (col == 0) {
        #pragma unroll
        for (int t = 0; t < 2; ++t)
            #pragma unroll
            for (int r = 0; r < 4; ++r) {
                const int n = n_base + t * 16 + quad * 4 + r;
                const size_t g = ((size_t)b * N + n) * MS + ms;   // [row][slot]
                wD[g] = bD[t][r];
                wI[g] = bI[t][r];
            }
    }
}

// Combine the 16 m-split slots and gather y_c.
// wD/wI are [row][slot]: lane = slot -> fully coalesced reads (4 rows x 64B
// contiguous per wave). 4-step shfl_xor reduce within each 16-lane group.
// Grid: 1024 blocks (16 rows/block).
__global__ __launch_bounds__(256)
void nn_combine(const float* __restrict__ wD, const int* __restrict__ wI,
                const void* __restrict__ ycptr,
                const unsigned short* __restrict__ tptr,
                void* __restrict__ outptr) {
    const bool is_bf16 = (tptr[0] == 0x4120);
    const int tid  = threadIdx.x;
    const int lane = tid & 63;
    const int wv   = tid >> 6;
    const int s    = lane & 15;
    const int row  = blockIdx.x * 16 + wv * 4 + (lane >> 4);

    float k  = wD[(size_t)row * MS + s];
    int   ix = wI[(size_t)row * MS + s];
    #pragma unroll
    for (int mask = 1; mask < 16; mask <<= 1) {
        float ok = __shfl_xor(k, mask, 64);
        int   oi = __shfl_xor(ix, mask, 64);
        if (ok > k || (ok == k && oi < ix)) { k = ok; ix = oi; }
    }

    if (s == 0) {
        const int b = row >> 12;  // N = 4096
        const size_t src = ((size_t)b * M + ix) * 3;
        if (is_bf16) {
            const unsigned short* yc = (const unsigned short*)ycptr;
            unsigned short* o = (unsigned short*)outptr;
            o[row*3+0] = yc[src+0];
            o[row*3+1] = yc[src+1];
            o[row*3+2] = yc[src+2];
        } else {
            const float* yc = (const float*)ycptr;
            float* o = (float*)outptr;
            o[row*3+0] = yc[src+0];
            o[row*3+1] = yc[src+1];
            o[row*3+2] = yc[src+2];
        }
    }
}

extern "C" void kernel_launch(void* const* d_in, const int* in_sizes, int n_in,
                              void* d_out, int out_size, void* d_ws, size_t ws_size,
                              hipStream_t stream) {
    const void* x  = d_in[0];
    const void* y  = d_in[1];
    const void* yc = d_in[2];
    const unsigned short* t = (const unsigned short*)d_in[3];

    float* wD = (float*)d_ws;
    int*   wI = (int*)((char*)d_ws + WS_WI);

    y_prepass<<<256, 256, 0, stream>>>(y, t, d_ws);
    nn_main<<<2048, 256, 0, stream>>>(x, y, t, d_ws);
    nn_combine<<<1024, 256, 0, stream>>>(wD, wI, yc, t, d_out);
}

// Round 5
// 94.686 us; speedup vs baseline: 2.1850x; 1.0546x over previous
//
#include <hip/hip_runtime.h>

#define B 4
#define N 4096
#define M 4096
#define C 32
#define BN (B * N)
#define MS 16            // m-splits; each split covers M/MS = 256 rows = 16 m-tiles

typedef short bf16x8 __attribute__((ext_vector_type(8)));  // 8 bf16 in 4 VGPRs
typedef float f32x4  __attribute__((ext_vector_type(4)));
typedef unsigned int u32x4 __attribute__((ext_vector_type(4)));

// Workspace layout (bytes). ~5.2 MB.
// wD/wI are SLOT-MAJOR [slot][row]: each block writes a private contiguous
// 1-KB run (round-4's [row][slot] layout caused ~8x cross-XCD write
// amplification: 64-B lines co-owned by 16 blocks -> WRITE_SIZE 17.7 MB).
#define WS_WI ((size_t)MS * BN * 4)                      // wD @ 0, wI @ WS_WI
#define WS_YP (WS_WI * 2)                                // y planes, chunk-major
// plane layout: [(b*16+chunk)*3 + p] * 8192 bf16 elems (chunk = 256 m-rows,
// 16 KB per plane-chunk, 3 plane-chunks contiguous = one 48-KB LDS memcpy)
#define WS_Y2 (WS_YP + (size_t)B * M * C * 3 * 2)        // -0.5*y2 (f32)

__device__ __forceinline__ float bf16lo(unsigned int u) { return __uint_as_float(u << 16); }
__device__ __forceinline__ float bf16hi(unsigned int u) { return __uint_as_float(u & 0xffff0000u); }

// Exact 3-way truncation split of 8 f32 values into 3 bf16x8 planes.
// f32 mantissa = 24 bits; each plane captures >=8 bits and each residual
// subtraction is exact, so f = h + m + l EXACTLY.
__device__ __forceinline__ void split3(const float f[8], bf16x8& h, bf16x8& m, bf16x8& l) {
    u32x4 hw, mw, lw;
    #pragma unroll
    for (int p = 0; p < 4; ++p) {
        const float f0 = f[2*p], f1 = f[2*p+1];
        const unsigned int h0 = __float_as_uint(f0) & 0xffff0000u;
        const unsigned int h1 = __float_as_uint(f1) & 0xffff0000u;
        hw[p] = h1 | (h0 >> 16);
        const float r0 = f0 - __uint_as_float(h0);
        const float r1 = f1 - __uint_as_float(h1);
        const unsigned int m0 = __float_as_uint(r0) & 0xffff0000u;
        const unsigned int m1 = __float_as_uint(r1) & 0xffff0000u;
        mw[p] = m1 | (m0 >> 16);
        const float s0 = r0 - __uint_as_float(m0);
        const float s1 = r1 - __uint_as_float(m1);
        lw[p] = (__float_as_uint(s1) & 0xffff0000u) | (__float_as_uint(s0) >> 16);
    }
    h = __builtin_bit_cast(bf16x8, hw);
    m = __builtin_bit_cast(bf16x8, mw);
    l = __builtin_bit_cast(bf16x8, lw);
}

// Pre-pass (f32 mode only): split y into 3 bf16 planes (chunk-major layout
// matching nn_main's 48-KB LDS stage) + compute -0.5*y2.
// Grid: 256 blocks x 256 threads = 65536 = B*M*4; each thread handles 8 elems.
__global__ __launch_bounds__(256)
void y_prepass(const void* __restrict__ yptr, const unsigned short* __restrict__ tptr,
               void* __restrict__ ws) {
    if (tptr[0] == 0x4120) return;   // bf16 inputs: planes unused
    unsigned short* yp = (unsigned short*)((char*)ws + WS_YP);
    float*          y2 = (float*)((char*)ws + WS_Y2);

    const int gid = blockIdx.x * 256 + threadIdx.x;
    const int row = gid >> 2;        // b*M + m
    const int seg = gid & 3;
    const int b   = row >> 12;       // M = 4096
    const int m   = row & 4095;
    const int chunk = m >> 8;
    const int mr    = m & 255;
    const float* p = (const float*)yptr + (size_t)row * C + seg * 8;
    float4 v0 = *(const float4*)p;
    float4 v1 = *(const float4*)(p + 4);
    const float f[8] = {v0.x, v0.y, v0.z, v0.w, v1.x, v1.y, v1.z, v1.w};

    bf16x8 h, m_, l;
    split3(f, h, m_, l);
    const size_t base = (size_t)((b * 16 + chunk) * 3) * 8192 + mr * 32 + seg * 8;
    *(bf16x8*)(yp + base)            = h;
    *(bf16x8*)(yp + base + 8192)     = m_;
    *(bf16x8*)(yp + base + 16384)    = l;

    float s = 0.f;
    #pragma unroll
    for (int k = 0; k < 8; ++k) s = fmaf(f[k], f[k], s);
    s += __shfl_xor(s, 1, 64);     // 4 consecutive lanes share a row
    s += __shfl_xor(s, 2, 64);
    if (seg == 0) y2[row] = -0.5f * s;
}

// Grid: 1024 blocks x 256 threads. LDS 49 KB -> 3 blocks/CU (12 waves/CU).
// bi -> ms = bi&15 (m-split of 256), nb = (bi>>4)&15 (256 n rows), b = bi>>8.
// Each wave: 64 n rows (4 MFMA n-tiles), scans 256 m via 16 m-tiles.
// B planes staged in LDS once per block (48-KB coalesced copy) -> inner loop
// B-loads are conflict-free ds_read_b128 with 24 MFMA each to hide them.
// This cuts the streamed L2/L3 traffic ~135 MB -> ~83 MB (the round-4
// bottleneck: MFMA-busy matched the issue floor while re-read traffic set
// the wall).
// Key = dot - y2/2 (argmax == argmin dist; x2 cancels). C-operand seeds -y2/2.
// f32 path: 6 MFMA terms (hh,hm,mh,mm,hl,lh); dropped ml/lm/ll are <=~3e-7,
// an order below the f32 accumulation noise (~7e-6) the reference itself
// carries -> argmax-neutral (harness-verified in rounds 3-4).
__global__ __launch_bounds__(256, 3)
void nn_main(const void* __restrict__ xptr, const void* __restrict__ yptr,
             const unsigned short* __restrict__ tptr, void* __restrict__ ws) {
    float* wD = (float*)ws;
    int*   wI = (int*)((char*)ws + WS_WI);
    const bool is_bf16 = (tptr[0] == 0x4120);  // bf16(10.0)=0x4120; f32 low half = 0x0000

    __shared__ uint4 bpl[3072];         // 48 KB: 3 B-plane chunks (h,m,l)
    __shared__ float y2s[256];          // -0.5*y2 for this m-split

    const int tid  = threadIdx.x;
    const int lane = tid & 63;
    const int wv   = tid >> 6;
    const int col  = lane & 15;
    const int quad = lane >> 4;
    const int bi   = blockIdx.x;
    const int ms   = bi & 15;
    const int nb   = (bi >> 4) & 15;
    const int b    = bi >> 8;
    const int n_base = nb * 256 + wv * 64;
    const int m0   = ms * 256;

    float bD[4][4];
    int   bI[4][4];
    #pragma unroll
    for (int t = 0; t < 4; ++t)
        #pragma unroll
        for (int r = 0; r < 4; ++r) { bD[t][r] = -__builtin_inff(); bI[t][r] = 0; }

    if (is_bf16) {
        const unsigned short* yp = (const unsigned short*)yptr;
        const unsigned short* xp = (const unsigned short*)xptr;

        // ---- stage -0.5*y2 for the 256 m rows of this split ----
        {
            const int r = tid;
            const uint4* p = (const uint4*)(yp + ((size_t)b * M + m0 + r) * C);
            float s = 0.f;
            #pragma unroll
            for (int i = 0; i < 4; ++i) {
                uint4 v = p[i];
                float f;
                f = bf16lo(v.x); s = fmaf(f, f, s); f = bf16hi(v.x); s = fmaf(f, f, s);
                f = bf16lo(v.y); s = fmaf(f, f, s); f = bf16hi(v.y); s = fmaf(f, f, s);
                f = bf16lo(v.z); s = fmaf(f, f, s); f = bf16hi(v.z); s = fmaf(f, f, s);
                f = bf16lo(v.w); s = fmaf(f, f, s); f = bf16hi(v.w); s = fmaf(f, f, s);
            }
            y2s[r] = -0.5f * s;
        }

        bf16x8 af[4];
        #pragma unroll
        for (int t = 0; t < 4; ++t)
            af[t] = *(const bf16x8*)(xp + ((size_t)b * N + n_base + t * 16 + col) * C + quad * 8);

        __syncthreads();

        const unsigned short* yb = yp + ((size_t)b * M + m0) * C;
        const size_t boff = (size_t)col * C + quad * 8;
        bf16x8 bfr = *(const bf16x8*)(yb + boff);
        for (int mt = 0; mt < 16; ++mt) {
            bf16x8 bnx = bfr;
            if (mt < 15) bnx = *(const bf16x8*)(yb + boff + (size_t)(mt + 1) * (16 * C));
            const float y2c  = y2s[mt * 16 + col];
            const int   mcur = m0 + mt * 16 + col;
            #pragma unroll
            for (int t = 0; t < 4; ++t) {
                f32x4 acc = {y2c, y2c, y2c, y2c};
                acc = __builtin_amdgcn_mfma_f32_16x16x32_bf16(af[t], bfr, acc, 0, 0, 0);
                #pragma unroll
                for (int r = 0; r < 4; ++r)
                    if (acc[r] > bD[t][r]) { bD[t][r] = acc[r]; bI[t][r] = mcur; }
            }
            bfr = bnx;
        }
    } else {
        // ============ f32 path: LDS-staged pre-split planes, 6 MFMA terms ============
        const uint4* src = (const uint4*)((char*)ws + WS_YP + (size_t)((b * 16 + ms) * 3) * 16384);
        const float* y2g = (const float*)((char*)ws + WS_Y2) + (size_t)b * M + m0;

        // 48-KB coalesced stage of the 3 plane-chunks + y2
        #pragma unroll
        for (int i = 0; i < 12; ++i) bpl[tid + i * 256] = src[tid + i * 256];
        y2s[tid] = y2g[tid];

        // A fragments: 3 planes per tile, split once in registers
        const float* xp = (const float*)xptr;
        bf16x8 ah[4], am[4], al[4];
        #pragma unroll
        for (int t = 0; t < 4; ++t) {
            const float* xr = xp + ((size_t)b * N + n_base + t * 16 + col) * C + quad * 8;
            float4 v0 = *(const float4*)xr;
            float4 v1 = *(const float4*)(xr + 4);
            const float xf[8] = {v0.x, v0.y, v0.z, v0.w, v1.x, v1.y, v1.z, v1.w};
            split3(xf, ah[t], am[t], al[t]);
        }

        __syncthreads();

        const unsigned short* lds = (const unsigned short*)bpl;
        const int fo = col * 32 + quad * 8;   // within-chunk fragment offset (elems)

        bf16x8 bh  = *(const bf16x8*)(lds + fo);
        bf16x8 bmi = *(const bf16x8*)(lds + 8192 + fo);
        bf16x8 bl  = *(const bf16x8*)(lds + 16384 + fo);
        for (int mt = 0; mt < 16; ++mt) {
            bf16x8 nh = bh, nm = bmi, nl = bl;
            if (mt < 15) {
                const int no = fo + (mt + 1) * (16 * 32);
                nh = *(const bf16x8*)(lds + no);
                nm = *(const bf16x8*)(lds + 8192 + no);
                nl = *(const bf16x8*)(lds + 16384 + no);
            }
            const float y2c  = y2s[mt * 16 + col];
            const int   mcur = m0 + mt * 16 + col;
            #pragma unroll
            for (int t = 0; t < 4; ++t) {
                f32x4 acc = {y2c, y2c, y2c, y2c};
                // 6 kept cross-terms, small-magnitude first
                acc = __builtin_amdgcn_mfma_f32_16x16x32_bf16(am[t], bmi, acc, 0, 0, 0);
                acc = __builtin_amdgcn_mfma_f32_16x16x32_bf16(ah[t], bl,  acc, 0, 0, 0);
                acc = __builtin_amdgcn_mfma_f32_16x16x32_bf16(al[t], bh,  acc, 0, 0, 0);
                acc = __builtin_amdgcn_mfma_f32_16x16x32_bf16(ah[t], bmi, acc, 0, 0, 0);
                acc = __builtin_amdgcn_mfma_f32_16x16x32_bf16(am[t], bh,  acc, 0, 0, 0);
                acc = __builtin_amdgcn_mfma_f32_16x16x32_bf16(ah[t], bh,  acc, 0, 0, 0);
                #pragma unroll
                for (int r = 0; r < 4; ++r)
                    if (acc[r] > bD[t][r]) { bD[t][r] = acc[r]; bI[t][r] = mcur; }
            }
            bh = nh; bmi = nm; bl = nl;
        }
    }

    // ---- butterfly over the 16 col-classes (lanes quad*16 + 0..15) ----
    #pragma unroll
    for (int mask = 1; mask < 16; mask <<= 1) {
        #pragma unroll
        for (int t = 0; t < 4; ++t)
            #pragma unroll
            for (int r = 0; r < 4; ++r) {
                float oD = __shfl_xor(bD[t][r], mask, 64);
                int   oI = __shfl_xor(bI[t][r], mask, 64);
                if (oD > bD[t][r] || (oD == bD[t][r] && oI < bI[t][r])) {
                    bD[t][r] = oD; bI[t][r] = oI;
                }
            }
    }

    // tracker (t,r) of lane-group quad holds row n_base + t*16 + quad*4 + r
    if (col == 0) {
        #pragma unroll
        for (int t = 0; t < 4; ++t)
            #pragma unroll
            for (int r = 0; r < 4; ++r) {
                const int n = n_base + t * 16 + quad * 4 + r;
                const size_t g = (size_t)ms * BN + (size_t)b * N + n;   // slot-major
                wD[g] = bD[t][r];
                wI[g] = bI[t][r];
            }
    }
}

// Combine the 16 m-split slots and gather y_c.
// Slot-major wD/wI: 16 lanes per slot-class; lane = s*4 + ro; 4 consecutive
// lanes read 16 B contiguous. 4-step shfl_xor reduce over s.
// Grid: 1024 blocks (16 rows/block).
__global__ __launch_bounds__(256)
void nn_combine(const float* __restrict__ wD, const int* __restrict__ wI,
                const void* __restrict__ ycptr,
                const unsigned short* __restrict__ tptr,
                void* __restrict__ outptr) {
    const bool is_bf16 = (tptr[0] == 0x4120);
    const int tid  = threadIdx.x;
    const int lane = tid & 63;
    const int wv   = tid >> 6;
    const int s    = lane >> 2;
    const int ro   = lane & 3;
    const int row  = blockIdx.x * 16 + wv * 4 + ro;

    float k  = wD[(size_t)s * BN + row];
    int   ix = wI[(size_t)s * BN + row];
    #pragma unroll
    for (int mask = 4; mask < 64; mask <<= 1) {
        float ok = __shfl_xor(k, mask, 64);
        int   oi = __shfl_xor(ix, mask, 64);
        if (ok > k || (ok == k && oi < ix)) { k = ok; ix = oi; }
    }

    if (s == 0) {
        const int b = row >> 12;  // N = 4096
        const size_t src = ((size_t)b * M + ix) * 3;
        if (is_bf16) {
            const unsigned short* yc = (const unsigned short*)ycptr;
            unsigned short* o = (unsigned short*)outptr;
            o[row*3+0] = yc[src+0];
            o[row*3+1] = yc[src+1];
            o[row*3+2] = yc[src+2];
        } else {
            const float* yc = (const float*)ycptr;
            float* o = (float*)outptr;
            o[row*3+0] = yc[src+0];
            o[row*3+1] = yc[src+1];
            o[row*3+2] = yc[src+2];
        }
    }
}

extern "C" void kernel_launch(void* const* d_in, const int* in_sizes, int n_in,
                              void* d_out, int out_size, void* d_ws, size_t ws_size,
                              hipStream_t stream) {
    const void* x  = d_in[0];
    const void* y  = d_in[1];
    const void* yc = d_in[2];
    const unsigned short* t = (const unsigned short*)d_in[3];

    float* wD = (float*)d_ws;
    int*   wI = (int*)((char*)d_ws + WS_WI);

    y_prepass<<<256, 256, 0, stream>>>(y, t, d_ws);
    nn_main<<<1024, 256, 0, stream>>>(x, y, t, d_ws);
    nn_combine<<<1024, 256, 0, stream>>>(wD, wI, yc, t, d_out);
}

// Round 6
// 92.597 us; speedup vs baseline: 2.2343x; 1.0226x over previous
//
#include <hip/hip_runtime.h>

#define B 4
#define N 4096
#define M 4096
#define C 32
#define BN (B * N)
#define MS 16            // m-splits; each split covers M/MS = 256 rows = 16 m-tiles

typedef short bf16x8 __attribute__((ext_vector_type(8)));  // 8 bf16 in 4 VGPRs
typedef float f32x4  __attribute__((ext_vector_type(4)));
typedef unsigned int u32x4 __attribute__((ext_vector_type(4)));

// Workspace layout (bytes). ~5.1 MB.
// wD/wI are SLOT-MAJOR [slot][row]: each block writes a private contiguous
// 1-KB run (a [row][slot] layout caused ~8x cross-XCD write amplification).
#define WS_WI  ((size_t)MS * BN * 4)                     // wD @ 0, wI @ WS_WI
#define WS_YHM (WS_WI * 2)                               // h+m planes, chunk-major
// h+m layout: per (b,chunk): 32 KB = 16 KB h || 16 KB m; within a plane-chunk:
// tile mt (1 KB) / row col (64 B) / seg slot 16 B, seg slot XOR-swizzled by
// ((col>>1)&3) so nn_main's ds_read_b128 fragment reads are 2-way (free).
#define WS_YL  (WS_YHM + (size_t)B * M * C * 2 * 2)      // l plane, linear [b][m][c]
#define WS_Y2  (WS_YL + (size_t)B * M * C * 2)           // -0.5*y2 (f32)

__device__ __forceinline__ float bf16lo(unsigned int u) { return __uint_as_float(u << 16); }
__device__ __forceinline__ float bf16hi(unsigned int u) { return __uint_as_float(u & 0xffff0000u); }

// Exact 3-way truncation split of 8 f32 values into 3 bf16x8 planes.
// f32 mantissa = 24 bits; each plane captures >=8 bits and each residual
// subtraction is exact, so f = h + m + l EXACTLY.
__device__ __forceinline__ void split3(const float f[8], bf16x8& h, bf16x8& m, bf16x8& l) {
    u32x4 hw, mw, lw;
    #pragma unroll
    for (int p = 0; p < 4; ++p) {
        const float f0 = f[2*p], f1 = f[2*p+1];
        const unsigned int h0 = __float_as_uint(f0) & 0xffff0000u;
        const unsigned int h1 = __float_as_uint(f1) & 0xffff0000u;
        hw[p] = h1 | (h0 >> 16);
        const float r0 = f0 - __uint_as_float(h0);
        const float r1 = f1 - __uint_as_float(h1);
        const unsigned int m0 = __float_as_uint(r0) & 0xffff0000u;
        const unsigned int m1 = __float_as_uint(r1) & 0xffff0000u;
        mw[p] = m1 | (m0 >> 16);
        const float s0 = r0 - __uint_as_float(m0);
        const float s1 = r1 - __uint_as_float(m1);
        lw[p] = (__float_as_uint(s1) & 0xffff0000u) | (__float_as_uint(s0) >> 16);
    }
    h = __builtin_bit_cast(bf16x8, hw);
    m = __builtin_bit_cast(bf16x8, mw);
    l = __builtin_bit_cast(bf16x8, lw);
}

// Pre-pass (f32 mode only): split y into 3 bf16 planes + compute -0.5*y2.
// h+m written chunk-major and seg-swizzled (matching nn_main's LDS reads);
// l written linear (streamed from global by nn_main).
// Grid: 256 blocks x 256 threads = 65536 = B*M*4; each thread handles 8 elems.
__global__ __launch_bounds__(256)
void y_prepass(const void* __restrict__ yptr, const unsigned short* __restrict__ tptr,
               void* __restrict__ ws) {
    if (tptr[0] == 0x4120) return;   // bf16 inputs: planes unused
    unsigned short* yhm = (unsigned short*)((char*)ws + WS_YHM);
    unsigned short* ylp = (unsigned short*)((char*)ws + WS_YL);
    float*          y2  = (float*)((char*)ws + WS_Y2);

    const int gid = blockIdx.x * 256 + threadIdx.x;
    const int row = gid >> 2;        // b*M + m
    const int seg = gid & 3;
    const int b   = row >> 12;       // M = 4096
    const int m   = row & 4095;
    const int chunk = m >> 8;
    const int mr    = m & 255;
    const int mt    = mr >> 4;
    const int colr  = mr & 15;
    const int segs  = seg ^ ((colr >> 1) & 3);   // bank swizzle (involution)
    const float* p = (const float*)yptr + (size_t)row * C + seg * 8;
    float4 v0 = *(const float4*)p;
    float4 v1 = *(const float4*)(p + 4);
    const float f[8] = {v0.x, v0.y, v0.z, v0.w, v1.x, v1.y, v1.z, v1.w};

    bf16x8 h, m_, l;
    split3(f, h, m_, l);
    // h/m: chunk-major + swizzled (elems)
    const size_t hmbase = (size_t)(b * 16 + chunk) * 16384 + mt * 512 + colr * 32 + segs * 8;
    *(bf16x8*)(yhm + hmbase)        = h;
    *(bf16x8*)(yhm + hmbase + 8192) = m_;
    // l: linear
    *(bf16x8*)(ylp + (size_t)row * C + seg * 8) = l;

    float s = 0.f;
    #pragma unroll
    for (int k = 0; k < 8; ++k) s = fmaf(f[k], f[k], s);
    s += __shfl_xor(s, 1, 64);     // 4 consecutive lanes share a row
    s += __shfl_xor(s, 2, 64);
    if (seg == 0) y2[row] = -0.5f * s;
}

// Grid: 1024 blocks x 256 threads. LDS 33 KB -> 4 blocks/CU (16 waves/CU, no
// occupancy tail). bi -> ms = bi&15 (256 m rows), nb = (bi>>4)&15 (256 n rows),
// b = bi>>8. Each wave: 64 n rows (4 MFMA n-tiles), scans 256 m via 16 m-tiles.
// h+m planes staged in LDS (32-KB linear memcpy of pre-swizzled data) -> the
// per-mt ds_read_b128 fragment reads hit 8 banks x 2 lanes = conflict-free.
// l plane streamed from global (feeds 2 of 6 terms), one-tile prefetch.
// Key = dot - y2/2 (argmax == argmin dist; x2 cancels). C-operand seeds -y2/2.
// f32 path: 6 MFMA terms (hh,hm,mh,mm,hl,lh); dropped ml/lm/ll are <=~3e-7,
// an order below the f32 accumulation noise (~7e-6) the reference itself
// carries -> argmax-neutral (harness-verified rounds 3-5).
__global__ __launch_bounds__(256, 4)
void nn_main(const void* __restrict__ xptr, const void* __restrict__ yptr,
             const unsigned short* __restrict__ tptr, void* __restrict__ ws) {
    float* wD = (float*)ws;
    int*   wI = (int*)((char*)ws + WS_WI);
    const bool is_bf16 = (tptr[0] == 0x4120);  // bf16(10.0)=0x4120; f32 low half = 0x0000

    __shared__ uint4 bpl[2048];         // 32 KB: h+m plane chunks
    __shared__ float y2s[256];          // -0.5*y2 for this m-split

    const int tid  = threadIdx.x;
    const int lane = tid & 63;
    const int wv   = tid >> 6;
    const int col  = lane & 15;
    const int quad = lane >> 4;
    const int bi   = blockIdx.x;
    const int ms   = bi & 15;
    const int nb   = (bi >> 4) & 15;
    const int b    = bi >> 8;
    const int n_base = nb * 256 + wv * 64;
    const int m0   = ms * 256;

    float bD[4][4];
    int   bI[4][4];
    #pragma unroll
    for (int t = 0; t < 4; ++t)
        #pragma unroll
        for (int r = 0; r < 4; ++r) { bD[t][r] = -__builtin_inff(); bI[t][r] = 0; }

    if (is_bf16) {
        const unsigned short* yp = (const unsigned short*)yptr;
        const unsigned short* xp = (const unsigned short*)xptr;

        // ---- stage -0.5*y2 for the 256 m rows of this split ----
        {
            const int r = tid;
            const uint4* p = (const uint4*)(yp + ((size_t)b * M + m0 + r) * C);
            float s = 0.f;
            #pragma unroll
            for (int i = 0; i < 4; ++i) {
                uint4 v = p[i];
                float f;
                f = bf16lo(v.x); s = fmaf(f, f, s); f = bf16hi(v.x); s = fmaf(f, f, s);
                f = bf16lo(v.y); s = fmaf(f, f, s); f = bf16hi(v.y); s = fmaf(f, f, s);
                f = bf16lo(v.z); s = fmaf(f, f, s); f = bf16hi(v.z); s = fmaf(f, f, s);
                f = bf16lo(v.w); s = fmaf(f, f, s); f = bf16hi(v.w); s = fmaf(f, f, s);
            }
            y2s[r] = -0.5f * s;
        }

        bf16x8 af[4];
        #pragma unroll
        for (int t = 0; t < 4; ++t)
            af[t] = *(const bf16x8*)(xp + ((size_t)b * N + n_base + t * 16 + col) * C + quad * 8);

        __syncthreads();

        const unsigned short* yb = yp + ((size_t)b * M + m0) * C;
        const size_t boff = (size_t)col * C + quad * 8;
        bf16x8 bfr = *(const bf16x8*)(yb + boff);
        for (int mt = 0; mt < 16; ++mt) {
            bf16x8 bnx = bfr;
            if (mt < 15) bnx = *(const bf16x8*)(yb + boff + (size_t)(mt + 1) * (16 * C));
            const float y2c  = y2s[mt * 16 + col];
            const int   mcur = m0 + mt * 16 + col;
            #pragma unroll
            for (int t = 0; t < 4; ++t) {
                f32x4 acc = {y2c, y2c, y2c, y2c};
                acc = __builtin_amdgcn_mfma_f32_16x16x32_bf16(af[t], bfr, acc, 0, 0, 0);
                #pragma unroll
                for (int r = 0; r < 4; ++r)
                    if (acc[r] > bD[t][r]) { bD[t][r] = acc[r]; bI[t][r] = mcur; }
            }
            bfr = bnx;
        }
    } else {
        // ====== f32 path: LDS h+m (swizzled), global-streamed l, 6 terms ======
        const uint4* src = (const uint4*)((char*)ws + WS_YHM + (size_t)(b * 16 + ms) * 32768);
        const float* y2g = (const float*)((char*)ws + WS_Y2) + (size_t)b * M + m0;
        const unsigned short* ylb = (const unsigned short*)((char*)ws + WS_YL) + ((size_t)b * M + m0) * C;

        // 32-KB linear stage (data pre-swizzled by y_prepass) + y2
        #pragma unroll
        for (int i = 0; i < 8; ++i) bpl[tid + i * 256] = src[tid + i * 256];
        y2s[tid] = y2g[tid];

        // A fragments: 3 planes per tile, split once in registers
        const float* xp = (const float*)xptr;
        bf16x8 ah[4], am[4], al[4];
        #pragma unroll
        for (int t = 0; t < 4; ++t) {
            const float* xr = xp + ((size_t)b * N + n_base + t * 16 + col) * C + quad * 8;
            float4 v0 = *(const float4*)xr;
            float4 v1 = *(const float4*)(xr + 4);
            const float xf[8] = {v0.x, v0.y, v0.z, v0.w, v1.x, v1.y, v1.z, v1.w};
            split3(xf, ah[t], am[t], al[t]);
        }

        __syncthreads();

        const unsigned short* lds = (const unsigned short*)bpl;
        // swizzled within-chunk fragment offset (elems): row col, seg quad
        const int fo   = col * 32 + (quad ^ ((col >> 1) & 3)) * 8;
        const size_t lo = (size_t)col * C + quad * 8;   // l-plane (linear)

        bf16x8 bh  = *(const bf16x8*)(lds + fo);
        bf16x8 bmi = *(const bf16x8*)(lds + 8192 + fo);
        bf16x8 bl  = *(const bf16x8*)(ylb + lo);
        for (int mt = 0; mt < 16; ++mt) {
            bf16x8 nh = bh, nm = bmi, nl = bl;
            if (mt < 15) {
                const int no = fo + (mt + 1) * 512;
                nh = *(const bf16x8*)(lds + no);
                nm = *(const bf16x8*)(lds + 8192 + no);
                nl = *(const bf16x8*)(ylb + lo + (size_t)(mt + 1) * 512);
            }
            const float y2c  = y2s[mt * 16 + col];
            const int   mcur = m0 + mt * 16 + col;
            #pragma unroll
            for (int t = 0; t < 4; ++t) {
                f32x4 acc = {y2c, y2c, y2c, y2c};
                // 6 kept cross-terms, small-magnitude first
                acc = __builtin_amdgcn_mfma_f32_16x16x32_bf16(am[t], bmi, acc, 0, 0, 0);
                acc = __builtin_amdgcn_mfma_f32_16x16x32_bf16(ah[t], bl,  acc, 0, 0, 0);
                acc = __builtin_amdgcn_mfma_f32_16x16x32_bf16(al[t], bh,  acc, 0, 0, 0);
                acc = __builtin_amdgcn_mfma_f32_16x16x32_bf16(ah[t], bmi, acc, 0, 0, 0);
                acc = __builtin_amdgcn_mfma_f32_16x16x32_bf16(am[t], bh,  acc, 0, 0, 0);
                acc = __builtin_amdgcn_mfma_f32_16x16x32_bf16(ah[t], bh,  acc, 0, 0, 0);
                #pragma unroll
                for (int r = 0; r < 4; ++r)
                    if (acc[r] > bD[t][r]) { bD[t][r] = acc[r]; bI[t][r] = mcur; }
            }
            bh = nh; bmi = nm; bl = nl;
        }
    }

    // ---- butterfly over the 16 col-classes (lanes quad*16 + 0..15) ----
    #pragma unroll
    for (int mask = 1; mask < 16; mask <<= 1) {
        #pragma unroll
        for (int t = 0; t < 4; ++t)
            #pragma unroll
            for (int r = 0; r < 4; ++r) {
                float oD = __shfl_xor(bD[t][r], mask, 64);
                int   oI = __shfl_xor(bI[t][r], mask, 64);
                if (oD > bD[t][r] || (oD == bD[t][r] && oI < bI[t][r])) {
                    bD[t][r] = oD; bI[t][r] = oI;
                }
            }
    }

    // tracker (t,r) of lane-group quad holds row n_base + t*16 + quad*4 + r
    if (col == 0) {
        #pragma unroll
        for (int t = 0; t < 4; ++t)
            #pragma unroll
            for (int r = 0; r < 4; ++r) {
                const int n = n_base + t * 16 + quad * 4 + r;
                const size_t g = (size_t)ms * BN + (size_t)b * N + n;   // slot-major
                wD[g] = bD[t][r];
                wI[g] = bI[t][r];
            }
    }
}

// Combine the 16 m-split slots and gather y_c.
// Slot-major wD/wI: lane = s*4 + ro; 4 consecutive lanes read 16 B contiguous.
// 4-step shfl_xor reduce over s. Grid: 1024 blocks (16 rows/block).
__global__ __launch_bounds__(256)
void nn_combine(const float* __restrict__ wD, const int* __restrict__ wI,
                const void* __restrict__ ycptr,
                const unsigned short* __restrict__ tptr,
                void* __restrict__ outptr) {
    const bool is_bf16 = (tptr[0] == 0x4120);
    const int tid  = threadIdx.x;
    const int lane = tid & 63;
    const int wv   = tid >> 6;
    const int s    = lane >> 2;
    const int ro   = lane & 3;
    const int row  = blockIdx.x * 16 + wv * 4 + ro;

    float k  = wD[(size_t)s * BN + row];
    int   ix = wI[(size_t)s * BN + row];
    #pragma unroll
    for (int mask = 4; mask < 64; mask <<= 1) {
        float ok = __shfl_xor(k, mask, 64);
        int   oi = __shfl_xor(ix, mask, 64);
        if (ok > k || (ok == k && oi < ix)) { k = ok; ix = oi; }
    }

    if (s == 0) {
        const int b = row >> 12;  // N = 4096
        const size_t src = ((size_t)b * M + ix) * 3;
        if (is_bf16) {
            const unsigned short* yc = (const unsigned short*)ycptr;
            unsigned short* o = (unsigned short*)outptr;
            o[row*3+0] = yc[src+0];
            o[row*3+1] = yc[src+1];
            o[row*3+2] = yc[src+2];
        } else {
            const float* yc = (const float*)ycptr;
            float* o = (float*)outptr;
            o[row*3+0] = yc[src+0];
            o[row*3+1] = yc[src+1];
            o[row*3+2] = yc[src+2];
        }
    }
}

extern "C" void kernel_launch(void* const* d_in, const int* in_sizes, int n_in,
                              void* d_out, int out_size, void* d_ws, size_t ws_size,
                              hipStream_t stream) {
    const void* x  = d_in[0];
    const void* y  = d_in[1];
    const void* yc = d_in[2];
    const unsigned short* t = (const unsigned short*)d_in[3];

    float* wD = (float*)d_ws;
    int*   wI = (int*)((char*)d_ws + WS_WI);

    y_prepass<<<256, 256, 0, stream>>>(y, t, d_ws);
    nn_main<<<1024, 256, 0, stream>>>(x, y, t, d_ws);
    nn_combine<<<1024, 256, 0, stream>>>(wD, wI, yc, t, d_out);
}